// Round 6
// baseline (252.305 us; speedup 1.0000x reference)
//
#include <hip/hip_runtime.h>

// FWHT N=4096/row fp32, BATCH=8192. H4096 = H16(b0-3) ⊗ H16(b4-7) ⊗ H16(b8-11).
// Persistent blocks: 4 rows/block, next-row global loads prefetched into regs and
// kept in flight across barriers (lgkmcnt-only barrier, no vmcnt drain).
//
// LDS swizzle: A(e) = e ^ (((e>>4)&7)<<2) ^ (((e>>8)&1)<<4)   (linear bijection;
// bits 0-1 untouched so 16B chunks stay contiguous/aligned).
// Bank math (verified per pattern):
//   phase-A ds_write_b128: quarter-wave covers all 8 bank-groups -> conflict-free
//   phase-B/C scalar b32:  exactly 2-way -> free (m136)
// Every scalar address = (precomputed base) ^ (compile-time const): 1 v_xor each.

#define NN 4096
#define RPB 4   // rows per block

__device__ __forceinline__ void h16(float r[16]) {
    #pragma unroll
    for (int s = 1; s < 16; s <<= 1) {
        #pragma unroll
        for (int m = 0; m < 16; ++m) {
            if (!(m & s)) {
                float x = r[m], y = r[m ^ s];
                r[m]     = x + y;
                r[m ^ s] = x - y;
            }
        }
    }
}

// lgkmcnt(0) + raw s_barrier: LDS-consistent barrier that does NOT drain vmcnt,
// so prefetch global loads stay in flight (m201-verified pattern).
__device__ __forceinline__ void lgkm_barrier() {
    asm volatile("s_waitcnt lgkmcnt(0)" ::: "memory");
    __builtin_amdgcn_s_barrier();
    asm volatile("" ::: "memory");
}

__global__ __launch_bounds__(256, 8) void fwht4096_kernel(const float* __restrict__ in,
                                                          float* __restrict__ out) {
    __shared__ float lds[NN];  // 16 KiB

    const int t   = threadIdx.x;
    const int chi = t >> 4;

    // Swizzled address bases (see header comment):
    const int wbase = (16 * t) ^ ((t & 7) << 2) ^ (((t >> 4) & 1) << 4); // phase A
    const int tb    = (256 * chi + (t & 15)) ^ ((chi & 1) << 4);         // phase B
    const int tc    = t ^ ((chi & 7) << 2);                              // phase C

    const long long row0 = (long long)blockIdx.x * RPB;
    const float* __restrict__ pin = in + row0 * NN + t * 16;

    float r[16], rn[16];

    // Head load: thread t owns e = 16t+i, 4x dwordx4 coalesced.
    #pragma unroll
    for (int j = 0; j < 4; ++j) {
        const float4 v = *reinterpret_cast<const float4*>(pin + 4 * j);
        r[4*j+0] = v.x; r[4*j+1] = v.y; r[4*j+2] = v.z; r[4*j+3] = v.w;
    }

    for (int it = 0; it < RPB; ++it) {
        // ---- Prefetch next row (stays in flight across the whole pipeline) ----
        if (it + 1 < RPB) {
            const float* __restrict__ pn = pin + (long long)(it + 1) * NN;
            #pragma unroll
            for (int j = 0; j < 4; ++j) {
                const float4 v = *reinterpret_cast<const float4*>(pn + 4 * j);
                rn[4*j+0] = v.x; rn[4*j+1] = v.y; rn[4*j+2] = v.z; rn[4*j+3] = v.w;
            }
        }

        // ---- Phase A: H16 on bits 0-3, then swizzled b128 writes ----
        h16(r);
        #pragma unroll
        for (int c = 0; c < 4; ++c) {
            *reinterpret_cast<float4*>(&lds[wbase ^ (4 * c)]) =
                make_float4(r[4*c], r[4*c+1], r[4*c+2], r[4*c+3]);
        }
        lgkm_barrier();

        // ---- Phase B: H16 on bits 4-7 (e = 256*chi + 16k + a) ----
        #pragma unroll
        for (int k = 0; k < 16; ++k)
            r[k] = lds[tb ^ ((16 * k) ^ ((k & 7) << 2))];
        h16(r);
        #pragma unroll
        for (int k = 0; k < 16; ++k)
            lds[tb ^ ((16 * k) ^ ((k & 7) << 2))] = r[k];
        lgkm_barrier();

        // ---- Phase C: H16 on bits 8-11 (e = 256k + t), store direct ----
        #pragma unroll
        for (int k = 0; k < 16; ++k)
            r[k] = lds[tc ^ ((256 * k) ^ ((k & 1) << 4))];
        h16(r);

        float* __restrict__ po = out + (row0 + it) * NN;
        #pragma unroll
        for (int k = 0; k < 16; ++k)
            po[k * 256 + t] = r[k];   // 64 consecutive dwords per wave-instr

        if (it + 1 < RPB) {
            // Protect LDS reuse: all waves' phase-C reads completed before the
            // barrier (lgkmcnt(0) inside); barrier only, no vmcnt drain.
            lgkm_barrier();
            #pragma unroll
            for (int i = 0; i < 16; ++i) r[i] = rn[i];
        }
    }
}

extern "C" void kernel_launch(void* const* d_in, const int* in_sizes, int n_in,
                              void* d_out, int out_size, void* d_ws, size_t ws_size,
                              hipStream_t stream) {
    const float* x = (const float*)d_in[0];
    float* y = (float*)d_out;
    const int rows = in_sizes[0] / NN;        // 8192
    const int blocks = rows / RPB;            // 2048 -> 8 blocks/CU
    fwht4096_kernel<<<blocks, 256, 0, stream>>>(x, y);
}

// Round 8
// 247.122 us; speedup vs baseline: 1.0210x; 1.0210x over previous
//
#include <hip/hip_runtime.h>

// FWHT N=4096/row fp32, BATCH=8192. H4096 = H16(b0-3) ⊗ H16(b4-7) ⊗ H16(b8-11).
// Persistent blocks, GRID-STRIDED row sweep (row = bid + it*grid): all co-resident
// blocks work in one contiguous ~32MiB stripe at a time -> L3-friendly sequential
// sweep (round-3 behavior) with round-6's conflict-free swizzled LDS.
//
// LDS swizzle: A(e) = e ^ (((e>>4)&7)<<2) ^ (((e>>8)&1)<<4)  (linear bijection,
// bits 0-1 untouched -> 16B chunks stay contiguous/aligned).
//   phase-A ds_write_b128: quarter-wave covers all 8 bank-groups -> conflict-free
//   phase-B/C scalar b32:  exactly 2-way -> free (m136)
// Measured round 6: SQ_LDS_BANK_CONFLICT == 0.  Keep unchanged.

#define NN 4096
#define RPB 4   // rows per block; grid = 8192/RPB = 2048 = 8 blocks/CU exactly

__device__ __forceinline__ void h16(float r[16]) {
    #pragma unroll
    for (int s = 1; s < 16; s <<= 1) {
        #pragma unroll
        for (int m = 0; m < 16; ++m) {
            if (!(m & s)) {
                float x = r[m], y = r[m ^ s];
                r[m]     = x + y;
                r[m ^ s] = x - y;
            }
        }
    }
}

// lgkmcnt(0) + raw s_barrier: LDS-consistent barrier that does NOT drain vmcnt,
// so prefetch global loads stay in flight (m201-verified pattern).
__device__ __forceinline__ void lgkm_barrier() {
    asm volatile("s_waitcnt lgkmcnt(0)" ::: "memory");
    __builtin_amdgcn_s_barrier();
    asm volatile("" ::: "memory");
}

__global__ __launch_bounds__(256, 8) void fwht4096_kernel(const float* __restrict__ in,
                                                          float* __restrict__ out) {
    __shared__ float lds[NN];  // 16 KiB

    const int t   = threadIdx.x;
    const int chi = t >> 4;

    // Swizzled address bases:
    const int wbase = (16 * t) ^ ((t & 7) << 2) ^ (((t >> 4) & 1) << 4); // phase A
    const int tb    = (256 * chi + (t & 15)) ^ ((chi & 1) << 4);         // phase B
    const int tc    = t ^ ((chi & 7) << 2);                              // phase C

    const int grid = gridDim.x;                     // 2048
    const long long rowStep = (long long)grid * NN; // stripe stride in elements

    const float* __restrict__ pin = in + (long long)blockIdx.x * NN + t * 16;

    float r[16], rn[16];

    // Head load: thread t owns e = 16t+i, 4x dwordx4 coalesced.
    #pragma unroll
    for (int j = 0; j < 4; ++j) {
        const float4 v = *reinterpret_cast<const float4*>(pin + 4 * j);
        r[4*j+0] = v.x; r[4*j+1] = v.y; r[4*j+2] = v.z; r[4*j+3] = v.w;
    }

    for (int it = 0; it < RPB; ++it) {
        // ---- Prefetch next stripe's row (in flight across the whole pipeline) ----
        if (it + 1 < RPB) {
            const float* __restrict__ pn = pin + (long long)(it + 1) * rowStep;
            #pragma unroll
            for (int j = 0; j < 4; ++j) {
                const float4 v = *reinterpret_cast<const float4*>(pn + 4 * j);
                rn[4*j+0] = v.x; rn[4*j+1] = v.y; rn[4*j+2] = v.z; rn[4*j+3] = v.w;
            }
        }

        // ---- Phase A: H16 on bits 0-3, swizzled b128 writes ----
        h16(r);
        #pragma unroll
        for (int c = 0; c < 4; ++c) {
            *reinterpret_cast<float4*>(&lds[wbase ^ (4 * c)]) =
                make_float4(r[4*c], r[4*c+1], r[4*c+2], r[4*c+3]);
        }
        lgkm_barrier();

        // ---- Phase B: H16 on bits 4-7 (e = 256*chi + 16k + a) ----
        #pragma unroll
        for (int k = 0; k < 16; ++k)
            r[k] = lds[tb ^ ((16 * k) ^ ((k & 7) << 2))];
        h16(r);
        #pragma unroll
        for (int k = 0; k < 16; ++k)
            lds[tb ^ ((16 * k) ^ ((k & 7) << 2))] = r[k];
        lgkm_barrier();

        // ---- Phase C: H16 on bits 8-11 (e = 256k + t), store direct ----
        #pragma unroll
        for (int k = 0; k < 16; ++k)
            r[k] = lds[tc ^ ((256 * k) ^ ((k & 1) << 4))];
        h16(r);

        float* __restrict__ po = out + (long long)blockIdx.x * NN
                                     + (long long)it * rowStep;
        #pragma unroll
        for (int k = 0; k < 16; ++k)
            po[k * 256 + t] = r[k];   // 64 consecutive dwords per wave-instr

        if (it + 1 < RPB) {
            // All waves' phase-C LDS reads retired (lgkmcnt(0)); no vmcnt drain.
            lgkm_barrier();
            #pragma unroll
            for (int i = 0; i < 16; ++i) r[i] = rn[i];
        }
    }
}

extern "C" void kernel_launch(void* const* d_in, const int* in_sizes, int n_in,
                              void* d_out, int out_size, void* d_ws, size_t ws_size,
                              hipStream_t stream) {
    const float* x = (const float*)d_in[0];
    float* y = (float*)d_out;
    const int rows = in_sizes[0] / NN;        // 8192
    const int blocks = rows / RPB;            // 2048 -> 8 blocks/CU
    fwht4096_kernel<<<blocks, 256, 0, stream>>>(x, y);
}